// Round 1
// baseline (143.499 us; speedup 1.0000x reference)
//
#include <hip/hip_runtime.h>

#define N 8192
#define D 256
#define INV_TAU 14.285714285714286f
#define EPSN 1e-6f

// fused-lse kernel geometry
#define RT 128            // rows per block (4 waves x 32 rows)
#define CT 64             // cols per LDS tile
#define CSPLIT 16         // column splits across blocks
#define CPB (N / CSPLIT)  // 512 cols per block
#define NTILES (CPB / CT) // 8 tiles
#define LDSS 264          // ushorts per LDS row: 256 + 8 pad (528 B, 16B aligned)

typedef unsigned int u32x4 __attribute__((ext_vector_type(4)));
typedef __bf16 bf16x8 __attribute__((ext_vector_type(8)));
typedef float f32x4 __attribute__((ext_vector_type(4)));

__device__ inline unsigned short f2bf(float x) {
    unsigned int u = __builtin_bit_cast(unsigned int, x);
    u += 0x7fffu + ((u >> 16) & 1u);   // round-to-nearest-even (finite inputs)
    return (unsigned short)(u >> 16);
}

__device__ inline float bf2f(unsigned short u) {
    return __builtin_bit_cast(float, (unsigned int)u << 16);
}

// One wave per row: normalize rows -> bf16 (A prescaled by INV_TAU so the MFMA
// output is directly the logit), fp32 diag, zero rowsum and out.
__global__ void ntx_prep(const float* __restrict__ im, const float* __restrict__ rec,
                         unsigned short* __restrict__ A, unsigned short* __restrict__ Bm,
                         float* __restrict__ diag, float* __restrict__ rowsum,
                         float* __restrict__ out) {
    const int wave = threadIdx.x >> 6;
    const int lane = threadIdx.x & 63;
    const int row  = blockIdx.x * 4 + wave;

    const float4 a = ((const float4*)(im  + (size_t)row * D))[lane];
    const float4 b = ((const float4*)(rec + (size_t)row * D))[lane];

    float ssa = a.x*a.x + a.y*a.y + a.z*a.z + a.w*a.w;
    float ssb = b.x*b.x + b.y*b.y + b.z*b.z + b.w*b.w;
    float dt  = a.x*b.x + a.y*b.y + a.z*b.z + a.w*b.w;
    #pragma unroll
    for (int o = 32; o; o >>= 1) {
        ssa += __shfl_xor(ssa, o);
        ssb += __shfl_xor(ssb, o);
        dt  += __shfl_xor(dt , o);
    }
    const float ra = 1.0f / fmaxf(sqrtf(ssa), EPSN);
    const float rb = 1.0f / fmaxf(sqrtf(ssb), EPSN);
    const float sa = ra * INV_TAU;   // fold INV_TAU into A (scale-invariant bf16 error)

    ushort4 pa, pb;
    pa.x = f2bf(a.x*sa); pa.y = f2bf(a.y*sa); pa.z = f2bf(a.z*sa); pa.w = f2bf(a.w*sa);
    pb.x = f2bf(b.x*rb); pb.y = f2bf(b.y*rb); pb.z = f2bf(b.z*rb); pb.w = f2bf(b.w*rb);
    *(ushort4*)(A  + (size_t)row * D + lane * 4) = pa;
    *(ushort4*)(Bm + (size_t)row * D + lane * 4) = pb;

    if (lane == 0) {
        diag[row]   = dt * ra * rb * INV_TAU;  // fp32 i2r[i,i]
        rowsum[row] = 0.0f;                    // ws is poisoned each launch
    }
    if (blockIdx.x == 0 && threadIdx.x == 0) out[0] = 0.0f;
}

// Fused GEMM + UNMASKED sum-of-exp per row (mask handled by ntx_cfin correction).
// grid = (N/RT) * CSPLIT blocks of 256 threads (4 waves).
__global__ __launch_bounds__(256, 2)
void ntx_lse(const unsigned short* __restrict__ A, const unsigned short* __restrict__ Bm,
             float* __restrict__ rowsum) {
    __shared__ __align__(16) unsigned short Bs[CT][LDSS];  // ~33 KB

    const int wave = threadIdx.x >> 6;
    const int lane = threadIdx.x & 63;
    const int g    = lane >> 4;    // 0..3 (k-quad / row-quad)
    const int n16  = lane & 15;    // 0..15

    const int rowblk = blockIdx.x & (N / RT - 1);   // 0..63
    const int colblk = blockIdx.x >> 6;             // 0..15
    const int row0 = rowblk * RT + wave * 32;       // this wave's 32 rows
    const int col0 = colblk * CPB;

    // A fragments for 32 rows x K=256 in registers (64 VGPRs).
    // A-operand layout: m = lane&15, k = (lane>>4)*8 + j
    bf16x8 afrag[2][8];
    #pragma unroll
    for (int rs = 0; rs < 2; ++rs) {
        const int r = row0 + rs * 16 + n16;
        #pragma unroll
        for (int k = 0; k < 8; ++k)
            afrag[rs][k] = __builtin_bit_cast(
                bf16x8, *(const u32x4*)(A + (size_t)r * D + k * 32 + g * 8));
    }

    float acc[2][4] = {{0.f,0.f,0.f,0.f},{0.f,0.f,0.f,0.f}};

    const int c32 = threadIdx.x & 31;   // 16B chunk within a 512B row
    const int rr  = threadIdx.x >> 5;   // 0..7

    // register double-buffer for B staging: preload tile 0
    u32x4 stg[8];
    #pragma unroll
    for (int p = 0; p < 8; ++p)
        stg[p] = *(const u32x4*)(Bm + (size_t)(col0 + p * 8 + rr) * D + c32 * 8);

    for (int t = 0; t < NTILES; ++t) {
        // commit prefetched tile to LDS
        #pragma unroll
        for (int p = 0; p < 8; ++p)
            *(u32x4*)(&Bs[p * 8 + rr][c32 * 8]) = stg[p];
        __syncthreads();

        // issue next tile's global loads; latency hides under this tile's compute
        if (t + 1 < NTILES) {
            const int coln = col0 + (t + 1) * CT;
            #pragma unroll
            for (int p = 0; p < 8; ++p)
                stg[p] = *(const u32x4*)(Bm + (size_t)(coln + p * 8 + rr) * D + c32 * 8);
        }

        #pragma unroll
        for (int cs = 0; cs < 4; ++cs) {
            // B-operand layout: n = lane&15, k = (lane>>4)*8 + j
            const int bc = cs * 16 + n16;
            bf16x8 bfrag[8];
            #pragma unroll
            for (int k = 0; k < 8; ++k)
                bfrag[k] = __builtin_bit_cast(
                    bf16x8, *(const u32x4*)(&Bs[bc][k * 32 + g * 8]));

            #pragma unroll
            for (int rs = 0; rs < 2; ++rs) {
                f32x4 c = {0.f, 0.f, 0.f, 0.f};
                #pragma unroll
                for (int k = 0; k < 8; ++k)
                    c = __builtin_amdgcn_mfma_f32_16x16x32_bf16(
                            afrag[rs][k], bfrag[k], c, 0, 0, 0);
                // epilogue: unmasked exp accumulate (c is already the logit)
                #pragma unroll
                for (int q = 0; q < 4; ++q)
                    acc[rs][q] += __expf(c[q]);
            }
        }
        __syncthreads();
    }

    // reduce partial row sums across the 16 lanes sharing each row group
    #pragma unroll
    for (int rs = 0; rs < 2; ++rs)
        #pragma unroll
        for (int q = 0; q < 4; ++q) {
            float v = acc[rs][q];
            v += __shfl_xor(v, 1);
            v += __shfl_xor(v, 2);
            v += __shfl_xor(v, 4);
            v += __shfl_xor(v, 8);
            if (n16 == 0)
                atomicAdd(&rowsum[row0 + rs * 16 + g * 4 + q], v);
        }
}

// Correction + finish: subtract same-label off-diagonal exps (~8 per row),
// then loss = mean(log(rowsum - corr) - diag) via one atomic per block.
// grid = N/16 blocks of 256 threads; each wave owns 4 rows.
__global__ void ntx_cfin(const unsigned short* __restrict__ A,
                         const unsigned short* __restrict__ Bm,
                         const int* __restrict__ labels,
                         const float* __restrict__ diag,
                         const float* __restrict__ rowsum,
                         float* __restrict__ out) {
    __shared__ float red[4];
    const int wave = threadIdx.x >> 6;
    const int lane = threadIdx.x & 63;
    const int r0 = blockIdx.x * 16 + wave * 4;   // 4 rows per wave

    int lab[4];
    float af[4][4];
    #pragma unroll
    for (int r = 0; r < 4; ++r) {
        lab[r] = labels[r0 + r];
        const ushort4 av = *(const ushort4*)(A + (size_t)(r0 + r) * D + lane * 4);
        af[r][0] = bf2f(av.x); af[r][1] = bf2f(av.y);
        af[r][2] = bf2f(av.z); af[r][3] = bf2f(av.w);
    }
    float corr[4] = {0.f, 0.f, 0.f, 0.f};

    // scan all labels once per wave (int4 per lane), ballot out the matches
    for (int it = 0; it < N / 256; ++it) {
        const int4 lv = ((const int4*)labels)[it * 64 + lane];
        #pragma unroll
        for (int s = 0; s < 4; ++s) {
            const int jl = (s == 0) ? lv.x : (s == 1) ? lv.y : (s == 2) ? lv.z : lv.w;
            #pragma unroll
            for (int r = 0; r < 4; ++r) {
                unsigned long long bm = __ballot(jl == lab[r]);
                while (bm) {
                    const int b = __ffsll((unsigned long long)bm) - 1;
                    bm &= bm - 1;
                    const int j = (it * 64 + b) * 4 + s;
                    if (j == r0 + r) continue;   // keep the diagonal
                    const ushort4 bv = *(const ushort4*)(Bm + (size_t)j * D + lane * 4);
                    float d = af[r][0]*bf2f(bv.x) + af[r][1]*bf2f(bv.y)
                            + af[r][2]*bf2f(bv.z) + af[r][3]*bf2f(bv.w);
                    #pragma unroll
                    for (int o = 32; o; o >>= 1) d += __shfl_xor(d, o);
                    corr[r] += __expf(d);        // d is the logit (A prescaled)
                }
            }
        }
    }

    if (lane == 0) {
        float s = 0.f;
        #pragma unroll
        for (int r = 0; r < 4; ++r)
            s += logf(rowsum[r0 + r] - corr[r]) - diag[r0 + r];
        red[wave] = s;
    }
    __syncthreads();
    if (threadIdx.x == 0)
        atomicAdd(out, (red[0] + red[1] + red[2] + red[3]) * (1.0f / (float)N));
}

extern "C" void kernel_launch(void* const* d_in, const int* in_sizes, int n_in,
                              void* d_out, int out_size, void* d_ws, size_t ws_size,
                              hipStream_t stream) {
    const float* im     = (const float*)d_in[0];
    const float* rec    = (const float*)d_in[1];
    const int*   labels = (const int*)d_in[2];
    float* out = (float*)d_out;

    unsigned short* A  = (unsigned short*)d_ws;           // 4 MB bf16 im_n * INV_TAU
    unsigned short* Bm = A + (size_t)N * D;               // 4 MB bf16 rec_n
    float* diag   = (float*)(Bm + (size_t)N * D);         // 32 KB
    float* rowsum = diag + N;                             // 32 KB

    ntx_prep<<<N / 4, 256, 0, stream>>>(im, rec, A, Bm, diag, rowsum, out);
    ntx_lse<<<(N / RT) * CSPLIT, 256, 0, stream>>>(A, Bm, rowsum);
    ntx_cfin<<<N / 16, 256, 0, stream>>>(A, Bm, labels, diag, rowsum, out);
}